// Round 7
// baseline (169.521 us; speedup 1.0000x reference)
//
#include <hip/hip_runtime.h>

// Levenshtein edit distance, ref (512,B) x hyp (512,B), B=1024, unit costs.
// Anti-diagonal wavefront, one 64-lane wave per batch element, 8 cells/lane,
// PACKED 2 cells per 32-bit register (VOP3P 16-bit SIMD), vcc-free.
//
// Biased relative domain (r2-verified exact): w = v - d + 1024, w in [0,1024].
//   diagonal move: w_new = A2s + nq - 2   (nq = ref!=hyp)
//   ins/del move:  w_new = min(A1s, A1)   (no +1 in this domain)
// i=0 boundary: constant 1024 injected via DPP old (high half feeds the
// pair-0 alignbit seam). j=0 boundary emerges from fake-init 0x3FFF
// (decays <=2/step -> >=14337 at the end, never collides with real <=1024).
// cand >= 0 always (on diag delta<=1022, w >= 1024-delta >= 2) -> u16-safe.
//
// Per step: 3 DPP + 4 pairs x (3 alignbit + 6 pk ops) = 39 VALU, no vcc,
// token-queue shift IS the alignbit result (zero movs).
// hyp column staged in LDS (r6 win, kept).

#define RLEN 512
#define HLEN 512
#define BATCH 1024
#define FAKE2 0x3FFF3FFF    // packed fake-infinity
#define BIASHI 0x04000000   // 1024 in high half: DPP old for value seams

typedef unsigned short v2u __attribute__((ext_vector_type(2)));

// lane L gets src from lane L-1; lane 0 gets `old` (gfx9 DPP WAVE_SHR1,
// bound_ctrl=false). HW-verified rounds 3-6.
__device__ __forceinline__ int dpp_shr1(int old, int src) {
  return __builtin_amdgcn_update_dpp(old, src, 0x138, 0xF, 0xF, false);
}
// funnel shift: {hi,lo} >> 16 -> dst = (lo.hi, hi.lo) = cells (2p-1, 2p)
__device__ __forceinline__ unsigned algn(int hi, int lo) {
  return __builtin_amdgcn_alignbit((unsigned)hi, (unsigned)lo, 16);
}
__device__ __forceinline__ v2u asv(unsigned x) { return __builtin_bit_cast(v2u, x); }
__device__ __forceinline__ unsigned asu(v2u x) { return __builtin_bit_cast(unsigned, x); }
__device__ __forceinline__ v2u vmin(v2u a, v2u b) { return __builtin_elementwise_min(a, b); }

// A2/A1/AN: int[4] packed diagonals (rel-biased). ht: int[4] packed token
// queue. Shifted queue hts = this step's compare tokens AND the new queue.
#define STEP(A2, A1, AN, tok)                                           \
  {                                                                     \
    int dA1 = dpp_shr1(BIASHI, A1[3]);                                  \
    int dA2 = dpp_shr1(BIASHI, A2[3]);                                  \
    int dHT = dpp_shr1((tok) << 16, ht[3]);                             \
    unsigned h0 = algn(ht[0], dHT);                                     \
    unsigned h1 = algn(ht[1], ht[0]);                                   \
    unsigned h2 = algn(ht[2], ht[1]);                                   \
    unsigned h3 = algn(ht[3], ht[2]);                                   \
    v2u a1s0 = asv(algn(A1[0], dA1));                                   \
    v2u a1s1 = asv(algn(A1[1], A1[0]));                                 \
    v2u a1s2 = asv(algn(A1[2], A1[1]));                                 \
    v2u a1s3 = asv(algn(A1[3], A1[2]));                                 \
    v2u a2s0 = asv(algn(A2[0], dA2));                                   \
    v2u a2s1 = asv(algn(A2[1], A2[0]));                                 \
    v2u a2s2 = asv(algn(A2[2], A2[1]));                                 \
    v2u a2s3 = asv(algn(A2[3], A2[2]));                                 \
    v2u nq0 = vmin(rt[0] - asv(h0), onep);                              \
    v2u nq1 = vmin(rt[1] - asv(h1), onep);                              \
    v2u nq2 = vmin(rt[2] - asv(h2), onep);                              \
    v2u nq3 = vmin(rt[3] - asv(h3), onep);                              \
    v2u c0 = a2s0 + nq0 - twop;                                         \
    v2u c1 = a2s1 + nq1 - twop;                                         \
    v2u c2 = a2s2 + nq2 - twop;                                         \
    v2u c3 = a2s3 + nq3 - twop;                                         \
    AN[0] = (int)asu(vmin(vmin(a1s0, asv((unsigned)A1[0])), c0));       \
    AN[1] = (int)asu(vmin(vmin(a1s1, asv((unsigned)A1[1])), c1));       \
    AN[2] = (int)asu(vmin(vmin(a1s2, asv((unsigned)A1[2])), c2));       \
    AN[3] = (int)asu(vmin(vmin(a1s3, asv((unsigned)A1[3])), c3));       \
    ht[0] = (int)h0; ht[1] = (int)h1; ht[2] = (int)h2; ht[3] = (int)h3; \
  }

__global__ void __launch_bounds__(64)
edit_distance_kernel(const int* __restrict__ ref,
                     const int* __restrict__ hyp,
                     float* __restrict__ out) {
  const int b = blockIdx.x;        // one wave (block of 64) per batch element
  const int lane = threadIdx.x;    // 0..63

  // Stage this problem's hyp column into LDS (one-time; r6 win).
  __shared__ int hyp_s[HLEN];
#pragma unroll
  for (int c = 0; c < HLEN / 64; ++c)
    hyp_s[c * 64 + lane] = hyp[(c * 64 + lane) * BATCH + b];

  // Packed static ref tokens: pair p = cells (lane*8+2p, lane*8+2p+1).
  v2u rt[4];
#pragma unroll
  for (int p = 0; p < 4; ++p) {
    unsigned lo = (unsigned)ref[(lane * 8 + 2 * p) * BATCH + b];
    unsigned hi = (unsigned)ref[(lane * 8 + 2 * p + 1) * BATCH + b];
    rt[p] = asv(lo | (hi << 16));
  }

  __syncthreads();  // hyp_s visible

  const v2u onep = {1, 1};
  const v2u twop = {2, 2};

  // Rotating packed diagonal buffers + packed token queue.
  int A[4], Bv[4], Cv[4], ht[4];
#pragma unroll
  for (int p = 0; p < 4; ++p) { A[p] = FAKE2; Bv[p] = FAKE2; ht[p] = 0x03FF03FF; }
  if (lane == 0) Bv[0] = 0x3FFF0400;  // cell 0 on diag 1: D[1][0]=1 -> w=1024

  // Step d injects token hyp0[d-2] at the seam (consumed by cell 0, j=d-1).
  int d = 2;
  int t0 = hyp_s[0];
  int t1 = hyp_s[1];
  int t2 = hyp_s[2];

  // 1023 diagonal steps (d = 2..1024), 3 per iteration, 341 iterations.
  for (int it = 0; it < 341; ++it) {
    int n0 = hyp_s[min(d + 1, HLEN - 1)];  // prefetch next iter's injections
    int n1 = hyp_s[min(d + 2, HLEN - 1)];
    int n2 = hyp_s[min(d + 3, HLEN - 1)];
    STEP(A, Bv, Cv, t0);   // diag d
    STEP(Bv, Cv, A, t1);   // diag d+1
    STEP(Cv, A, Bv, t2);   // diag d+2
    d += 3;
    t0 = n0; t1 = n1; t2 = n2;
  }

  // Answer: diag 1024 in Bv; cell 511 = lane 63, pair 3, HIGH half.
  // At d = 1024 = BIAS, w = v exactly.
  if (lane == 63) out[b] = (float)(((unsigned)Bv[3]) >> 16);
}

extern "C" void kernel_launch(void* const* d_in, const int* in_sizes, int n_in,
                              void* d_out, int out_size, void* d_ws, size_t ws_size,
                              hipStream_t stream) {
  const int* ref = (const int*)d_in[0];
  const int* hyp = (const int*)d_in[1];
  float* out = (float*)d_out;
  edit_distance_kernel<<<BATCH, 64, 0, stream>>>(ref, hyp, out);
}

// Round 8
// 130.838 us; speedup vs baseline: 1.2957x; 1.2957x over previous
//
#include <hip/hip_runtime.h>

// Levenshtein edit distance, ref (512,B) x hyp (512,B), B=1024, unit costs.
// Anti-diagonal wavefront, one 64-lane wave per problem, 8 cells/lane packed
// 2-per-register in PARITY-STRIDED layout: reg p = cells {p, p+4} (lo,hi).
// Shift-by-one-cell is then a pure register rename for pairs 1..3; only
// pair 0 needs 1 DPP + 1 alignbit per array. VOP3P ops forced via inline asm
// (r7 evidence: compiler scalarizes ushort2 arithmetic ~2.5x).
//
// Biased relative domain (exact, r7-verified): w = v - d + 1024 in [0,1024].
//   AN = min(a1s, A1, a2s + nq - 2),  nq = (ref!=hyp) via min_u16(xor,1)
// i=0 boundary: constant 1024 via DPP old operand high half. j=0 boundary:
// fake-init 0x3FFF (decays <=2/step -> >=14337 at end, never beats real).
// nq-2 added as 0xFFFE per lane (mod-2^16 exact; true result >= 0).
//
// Issue model (r6/r7): busy cyc/step = 2 x instr/step at 1 wave/SIMD.
// This kernel: 2 DPP + 2 alignbit + 4 xor + 20 pk = 28 VALU/step.

#define HLEN 512
#define BATCH 1024
#define FAKE2  0x3FFF3FFFu  // packed fake-infinity
#define SENT2  0x03FF03FFu  // packed token sentinel (real tokens < 1000)
#define BIASHI 0x04000000u  // 1024 in high half: DPP old for value seam
#define ONE2   0x00010001u
#define NEG22  0xFFFEFFFEu  // -2 per 16-bit lane

// lane L gets src from lane L-1; lane 0 gets `old` (gfx9 DPP WAVE_SHR1,
// bound_ctrl=false). HW-verified rounds 3-7.
__device__ __forceinline__ unsigned dpp_shr1(unsigned old, unsigned src) {
  return (unsigned)__builtin_amdgcn_update_dpp((int)old, (int)src, 0x138, 0xF, 0xF, false);
}
// {hi,lo} >> 16: result = {lo: lo.hi, hi: hi.lo}
__device__ __forceinline__ unsigned algn(unsigned hi, unsigned lo) {
  return __builtin_amdgcn_alignbit(hi, lo, 16);
}
// Guaranteed single-instruction VOP3P (non-volatile: schedulable/CSE-able).
__device__ __forceinline__ unsigned pkmin(unsigned a, unsigned b) {
  unsigned d; asm("v_pk_min_u16 %0, %1, %2" : "=v"(d) : "v"(a), "v"(b)); return d;
}
__device__ __forceinline__ unsigned pkadd(unsigned a, unsigned b) {
  unsigned d; asm("v_pk_add_u16 %0, %1, %2" : "=v"(d) : "v"(a), "v"(b)); return d;
}

// One diagonal step. A2/A1/AN: unsigned[4] parity-packed diagonals.
// Q0..Q3: token queue regs, newest-first; after the step the new front is
// written into Q3 and the NEXT call passes args rotated right one position.
// Shifted values: a1s[p>=1] = A1[p-1], a2s[p>=1] = A2[p-1] (renames);
// a2s[0] = s0c (carried: last step's a1s[0]).
#define STEP(A2, A1, AN, Q0, Q1, Q2, Q3, tok)                          \
  {                                                                    \
    unsigned dA1 = dpp_shr1(BIASHI, A1[3]);                            \
    unsigned a1s0 = algn(A1[3], dA1);                                  \
    unsigned dHT = dpp_shr1((tok) << 16, Q3);                          \
    unsigned hn = algn(Q3, dHT);                                       \
    unsigned nq0 = pkmin(rt[0] ^ hn, one2);                            \
    unsigned c0  = pkadd(s0c, pkadd(nq0, neg2));                       \
    AN[0] = pkmin(pkmin(a1s0, A1[0]), c0);                             \
    unsigned nq1 = pkmin(rt[1] ^ Q0, one2);                            \
    unsigned c1  = pkadd(A2[0], pkadd(nq1, neg2));                     \
    AN[1] = pkmin(pkmin(A1[0], A1[1]), c1);                            \
    unsigned nq2 = pkmin(rt[2] ^ Q1, one2);                            \
    unsigned c2  = pkadd(A2[1], pkadd(nq2, neg2));                     \
    AN[2] = pkmin(pkmin(A1[1], A1[2]), c2);                            \
    unsigned nq3 = pkmin(rt[3] ^ Q2, one2);                            \
    unsigned c3  = pkadd(A2[2], pkadd(nq3, neg2));                     \
    AN[3] = pkmin(pkmin(A1[2], A1[3]), c3);                            \
    s0c = a1s0;                                                        \
    Q3 = hn;                                                           \
  }

__global__ void __launch_bounds__(64)
edit_distance_kernel(const int* __restrict__ ref,
                     const int* __restrict__ hyp,
                     float* __restrict__ out) {
  const int b = blockIdx.x;        // one wave (block of 64) per batch element
  const int lane = threadIdx.x;    // 0..63

  // Stage this problem's hyp column into LDS (r6 win).
  __shared__ unsigned hyp_s[HLEN];
#pragma unroll
  for (int c = 0; c < HLEN / 64; ++c)
    hyp_s[c * 64 + lane] = (unsigned)hyp[(c * 64 + lane) * BATCH + b];

  // Parity-packed static ref tokens: rt[p] = {cell lane*8+p, cell lane*8+p+4}.
  unsigned rt[4];
#pragma unroll
  for (int p = 0; p < 4; ++p) {
    unsigned lo = (unsigned)ref[(lane * 8 + p) * BATCH + b];
    unsigned hi = (unsigned)ref[(lane * 8 + p + 4) * BATCH + b];
    rt[p] = lo | (hi << 16);
  }

  __syncthreads();  // hyp_s visible

  const unsigned one2 = ONE2;
  const unsigned neg2 = NEG22;

  // Rotating parity-packed diagonal buffers.
  unsigned A[4], Bv[4], Cv[4];
#pragma unroll
  for (int p = 0; p < 4; ++p) { A[p] = FAKE2; Bv[p] = FAKE2; }
  if (lane == 0) Bv[0] = 0x3FFF0400u;  // cell 0 (lo half) on diag 1: w=1024

  // Token queue (parity-packed), all sentinels.
  unsigned q0 = SENT2, q1 = SENT2, q2 = SENT2, q3 = SENT2;

  // Carried shifted-A2 seam: shifted diag-0 (all fake, lane0 lo = 1024).
  unsigned s0c;
  { unsigned dA0 = dpp_shr1(BIASHI, A[3]); s0c = algn(A[3], dA0); }

  // Current-iteration injection tokens (step d injects hyp0[d-2], clamped;
  // clamp region only feeds j>512 garbage cells — r6/r7-verified).
  unsigned t[12], tn[12];
#pragma unroll
  for (int j = 0; j < 12; ++j) t[j] = hyp_s[j];  // d = 2..13 -> idx 0..11

  // 85 iterations x 12 steps = d = 2..1021.
  for (int it = 0; it < 85; ++it) {
    const int base = 12 + it * 12;  // next iter's first token index
#pragma unroll
    for (int j = 0; j < 12; ++j) tn[j] = hyp_s[min(base + j, HLEN - 1)];
    STEP(A, Bv, Cv, q0, q1, q2, q3, t[0]);
    STEP(Bv, Cv, A, q3, q0, q1, q2, t[1]);
    STEP(Cv, A, Bv, q2, q3, q0, q1, t[2]);
    STEP(A, Bv, Cv, q1, q2, q3, q0, t[3]);
    STEP(Bv, Cv, A, q0, q1, q2, q3, t[4]);
    STEP(Cv, A, Bv, q3, q0, q1, q2, t[5]);
    STEP(A, Bv, Cv, q2, q3, q0, q1, t[6]);
    STEP(Bv, Cv, A, q1, q2, q3, q0, t[7]);
    STEP(Cv, A, Bv, q0, q1, q2, q3, t[8]);
    STEP(A, Bv, Cv, q3, q0, q1, q2, t[9]);
    STEP(Bv, Cv, A, q2, q3, q0, q1, t[10]);
    STEP(Cv, A, Bv, q1, q2, q3, q0, t[11]);
#pragma unroll
    for (int j = 0; j < 12; ++j) t[j] = tn[j];
  }

  // Epilogue: d = 1022, 1023, 1024 (tokens all clamped -> garbage region).
  STEP(A, Bv, Cv, q0, q1, q2, q3, t[0]);
  STEP(Bv, Cv, A, q3, q0, q1, q2, t[1]);
  STEP(Cv, A, Bv, q2, q3, q0, q1, t[2]);

  // Answer: diag 1024 in Bv; cell 511 = lane 63, pair 3, HIGH half.
  // At d = 1024 = BIAS, w = v exactly.
  if (lane == 63) out[b] = (float)(Bv[3] >> 16);
}

extern "C" void kernel_launch(void* const* d_in, const int* in_sizes, int n_in,
                              void* d_out, int out_size, void* d_ws, size_t ws_size,
                              hipStream_t stream) {
  const int* ref = (const int*)d_in[0];
  const int* hyp = (const int*)d_in[1];
  float* out = (float*)d_out;
  edit_distance_kernel<<<BATCH, 64, 0, stream>>>(ref, hyp, out);
}